// Round 1
// baseline (2440.864 us; speedup 1.0000x reference)
//
#include <hip/hip_runtime.h>

// MS1: 64-layer reversible net, fused single-kernel recurrence.
// Y,Z (8192x256 each) evolve through 64 layers:
//   Z += H*tanh(Y @ K_j^T + b_j[256:]);  Y += H*tanh(-(Z @ K_j) + b_j[:256])
// Strategy: 256 blocks x 32 rows; fp32 master state in registers; fp16 hi/lo
// state copies in LDS; K pre-transposed + Ozaki-split to fp16 hi/lo in d_ws;
// 3-pass f16 MFMA (AhBh + AlBh + AhBl) ~= fp32 accuracy.

typedef _Float16 f16x8 __attribute__((ext_vector_type(8)));
typedef _Float16 f16x2 __attribute__((ext_vector_type(2)));
typedef float    f32x4 __attribute__((ext_vector_type(4)));

#define H_STEP 0.015625f   // 1/64

__device__ __forceinline__ float fast_tanh(float x) {
    // tanh(x) = (e^{2x}-1)/(e^{2x}+1); clamp so exp never overflows.
    float xc = fminf(fmaxf(x, -9.0f), 9.0f);
    float t  = __builtin_amdgcn_exp2f(xc * 2.8853900817779268f); // 2*log2(e)
    return (t - 1.0f) * __builtin_amdgcn_rcpf(t + 1.0f);
}

// LDS half-array index with XOR swizzle (byte ^= (row&7)<<4 in half units).
__device__ __forceinline__ int swz(int m, int k) {
    return (m << 8) + (k ^ ((m & 7) << 3));
}

// ---------------- prep: K[a][b][j] -> fragment-friendly half arrays ----------
// B1[j][n][k] = K[n][k][j]  (for Y @ K^T)
// B2[j][n][k] = K[k][n][j]  (for Z @ K)
__global__ __launch_bounds__(256) void prep_split(
    const float* __restrict__ K,
    _Float16* __restrict__ B1h, _Float16* __restrict__ B1l,
    _Float16* __restrict__ B2h, _Float16* __restrict__ B2l)
{
    __shared__ float tile[32][33][9];   // [aa][bb][jj], padded
    const int a0 = (blockIdx.x & 7) << 5;
    const int b0 = ((blockIdx.x >> 3) & 7) << 5;
    const int j0 = (blockIdx.x >> 6) << 3;
    const int t = threadIdx.x;

    for (int idx = t; idx < 8192; idx += 256) {
        const int jj = idx & 7, bb = (idx >> 3) & 31, aa = idx >> 8;
        tile[aa][bb][jj] = K[((size_t)(a0 + aa) * 256 + (b0 + bb)) * 64 + (j0 + jj)];
    }
    __syncthreads();

    // B1: n = a, k = b  (k contiguous)
    for (int idx = t; idx < 4096; idx += 256) {
        const int p = idx & 15, aa = (idx >> 4) & 31, jj = idx >> 9;
        const float f0 = tile[aa][2*p][jj], f1 = tile[aa][2*p+1][jj];
        const _Float16 h0 = (_Float16)f0, h1 = (_Float16)f1;
        const f16x2 hv = {h0, h1};
        const f16x2 lv = {(_Float16)(f0 - (float)h0), (_Float16)(f1 - (float)h1)};
        const size_t off = ((size_t)(j0 + jj) * 256 + (a0 + aa)) * 256 + (b0 + 2*p);
        *(f16x2*)(B1h + off) = hv;
        *(f16x2*)(B1l + off) = lv;
    }
    // B2: n = b, k = a  (k contiguous)
    for (int idx = t; idx < 4096; idx += 256) {
        const int p = idx & 15, bb = (idx >> 4) & 31, jj = idx >> 9;
        const float f0 = tile[2*p][bb][jj], f1 = tile[2*p+1][bb][jj];
        const _Float16 h0 = (_Float16)f0, h1 = (_Float16)f1;
        const f16x2 hv = {h0, h1};
        const f16x2 lv = {(_Float16)(f0 - (float)h0), (_Float16)(f1 - (float)h1)};
        const size_t off = ((size_t)(j0 + jj) * 256 + (b0 + bb)) * 256 + (a0 + 2*p);
        *(f16x2*)(B2h + off) = hv;
        *(f16x2*)(B2l + off) = lv;
    }
}

// ---------------- fused recurrence ----------------
// One half-layer: D = Ain @ B  (M=32,N=256,K=256 via 16x16x32 f16 MFMA, 3-split),
// then master += H*tanh(bias +/- D), write fp16 hi/lo of master to Aout LDS.
template<bool NEG>
__device__ __forceinline__ void half_layer(
    const _Float16* __restrict__ Ain_h, const _Float16* __restrict__ Ain_l,
    _Float16* __restrict__ Aout_h, _Float16* __restrict__ Aout_l,
    const _Float16* __restrict__ Bh, const _Float16* __restrict__ Bl,
    const float* __restrict__ bias,            // pre-offset: bvec + featbase*64 + j
    float (&M)[4][4],
    const int mt, const int nr, const int l15, const int hi4)
{
    f32x4 acc[4] = {{0.f,0.f,0.f,0.f},{0.f,0.f,0.f,0.f},
                    {0.f,0.f,0.f,0.f},{0.f,0.f,0.f,0.f}};
    const int arow = mt * 16 + l15;
#pragma unroll
    for (int s = 0; s < 8; ++s) {
        const int k0 = s * 32 + hi4 * 8;
        const f16x8 ah = *(const f16x8*)(Ain_h + swz(arow, k0));
        const f16x8 al = *(const f16x8*)(Ain_l + swz(arow, k0));
#pragma unroll
        for (int nt = 0; nt < 4; ++nt) {
            const int n = (nr * 4 + nt) * 16 + l15;
            const size_t boff = (size_t)n * 256 + k0;
            const f16x8 bh = *(const f16x8*)(Bh + boff);
            const f16x8 bl = *(const f16x8*)(Bl + boff);
            acc[nt] = __builtin_amdgcn_mfma_f32_16x16x32_f16(ah, bh, acc[nt], 0, 0, 0);
            acc[nt] = __builtin_amdgcn_mfma_f32_16x16x32_f16(al, bh, acc[nt], 0, 0, 0);
            acc[nt] = __builtin_amdgcn_mfma_f32_16x16x32_f16(ah, bl, acc[nt], 0, 0, 0);
        }
    }
#pragma unroll
    for (int nt = 0; nt < 4; ++nt) {
        const int n = (nr * 4 + nt) * 16 + l15;
        const float bv = bias[(size_t)n * 64];
#pragma unroll
        for (int q = 0; q < 4; ++q) {
            const int m = mt * 16 + hi4 * 4 + q;
            const float x = NEG ? (bv - acc[nt][q]) : (acc[nt][q] + bv);
            const float v = M[nt][q] + H_STEP * fast_tanh(x);
            M[nt][q] = v;
            const _Float16 vh = (_Float16)v;
            const int o = swz(m, n);
            Aout_h[o] = vh;
            Aout_l[o] = (_Float16)(v - (float)vh);
        }
    }
}

__global__ __launch_bounds__(512) void ms1_main(
    const float* __restrict__ Y0,
    const float* __restrict__ bvec,
    const _Float16* __restrict__ B1h, const _Float16* __restrict__ B1l,
    const _Float16* __restrict__ B2h, const _Float16* __restrict__ B2l,
    float* __restrict__ out)
{
    __shared__ _Float16 Yh[8192], Yl[8192], Zh[8192], Zl[8192];  // 64 KB total

    const int tid  = threadIdx.x;
    const int lane = tid & 63, w = tid >> 6;  // 8 waves
    const int mt = w & 1, nr = w >> 1;        // wave -> (m-tile, n-range)
    const int l15 = lane & 15, hi4 = lane >> 4;
    const size_t row0 = (size_t)blockIdx.x * 32;

    float Ym[4][4], Zm[4][4];   // fp32 master state, register-resident

#pragma unroll
    for (int nt = 0; nt < 4; ++nt) {
        const int n = (nr * 4 + nt) * 16 + l15;
#pragma unroll
        for (int q = 0; q < 4; ++q) {
            const int m = mt * 16 + hi4 * 4 + q;
            const size_t base = (row0 + m) * 512;
            const float y = Y0[base + n];
            const float z = Y0[base + 256 + n];
            Ym[nt][q] = y; Zm[nt][q] = z;
            const _Float16 yh = (_Float16)y;
            const int o = swz(m, n);
            Yh[o] = yh;
            Yl[o] = (_Float16)(y - (float)yh);
        }
    }
    __syncthreads();

    for (int j = 0; j < 64; ++j) {
        const size_t jb = (size_t)j << 16;  // j * 256*256
        // Z += H*tanh(Y @ K^T + b[256:])
        half_layer<false>(Yh, Yl, Zh, Zl, B1h + jb, B1l + jb,
                          bvec + 256 * 64 + j, Zm, mt, nr, l15, hi4);
        __syncthreads();
        // Y += H*tanh(b[:256] - Z @ K)
        half_layer<true>(Zh, Zl, Yh, Yl, B2h + jb, B2l + jb,
                         bvec + j, Ym, mt, nr, l15, hi4);
        __syncthreads();
    }

#pragma unroll
    for (int nt = 0; nt < 4; ++nt) {
        const int n = (nr * 4 + nt) * 16 + l15;
#pragma unroll
        for (int q = 0; q < 4; ++q) {
            const int m = mt * 16 + hi4 * 4 + q;
            const size_t base = (row0 + m) * 512;
            out[base + n]       = Ym[nt][q];
            out[base + 256 + n] = Zm[nt][q];
        }
    }
}

extern "C" void kernel_launch(void* const* d_in, const int* in_sizes, int n_in,
                              void* d_out, int out_size, void* d_ws, size_t ws_size,
                              hipStream_t stream) {
    (void)in_sizes; (void)n_in; (void)out_size;
    const float* Y0 = (const float*)d_in[0];
    const float* K  = (const float*)d_in[1];
    const float* b  = (const float*)d_in[2];

    const size_t ARR = (size_t)64 * 256 * 256;     // elements per half array
    if (ws_size < 4 * ARR * sizeof(_Float16)) return;  // visible failure, no corruption

    _Float16* B1h = (_Float16*)d_ws;
    _Float16* B1l = B1h + ARR;
    _Float16* B2h = B1l + ARR;
    _Float16* B2l = B2h + ARR;

    prep_split<<<512, 256, 0, stream>>>(K, B1h, B1l, B2h, B2l);
    ms1_main<<<256, 512, 0, stream>>>(Y0, b, B1h, B1l, B2h, B2l, (float*)d_out);
}

// Round 2
// 2030.906 us; speedup vs baseline: 1.2019x; 1.2019x over previous
//
#include <hip/hip_runtime.h>

// MS1: 64-layer reversible net, fused single-kernel recurrence.
//   Z += H*tanh(Y @ K_j^T + b_j[256:]);  Y += H*tanh(b_j[:256] - Z @ K_j)
// R2: 256 blocks x 32 rows, 1024 threads (16 waves) per block -> 4 waves/SIMD.
// fp32 master state in registers; fp16 hi/lo state in LDS (XOR-swizzled);
// K pre-transposed + Ozaki hi/lo split in d_ws; 3-pass f16 MFMA per GEMM.

typedef _Float16 f16x8 __attribute__((ext_vector_type(8)));
typedef _Float16 f16x2 __attribute__((ext_vector_type(2)));
typedef float    f32x4 __attribute__((ext_vector_type(4)));

#define H_STEP 0.015625f   // 1/64

__device__ __forceinline__ float fast_tanh(float x) {
    float xc = fminf(fmaxf(x, -9.0f), 9.0f);
    float t  = __builtin_amdgcn_exp2f(xc * 2.8853900817779268f); // 2x*log2(e)
    return (t - 1.0f) * __builtin_amdgcn_rcpf(t + 1.0f);
}

// LDS half-array index with XOR swizzle (16B-granular column rotation per row).
__device__ __forceinline__ int swz(int m, int k) {
    return (m << 8) + (k ^ ((m & 7) << 3));
}

// ---------------- prep: K[a][b][j] -> fragment-friendly half arrays ----------
// B1[j][n][k] = K[n][k][j]  (for Y @ K^T)
// B2[j][n][k] = K[k][n][j]  (for Z @ K)
__global__ __launch_bounds__(256) void prep_split(
    const float* __restrict__ K,
    _Float16* __restrict__ B1h, _Float16* __restrict__ B1l,
    _Float16* __restrict__ B2h, _Float16* __restrict__ B2l)
{
    __shared__ float tile[32][33][9];   // [aa][bb][jj], padded
    const int a0 = (blockIdx.x & 7) << 5;
    const int b0 = ((blockIdx.x >> 3) & 7) << 5;
    const int j0 = (blockIdx.x >> 6) << 3;
    const int t = threadIdx.x;

    for (int idx = t; idx < 8192; idx += 256) {
        const int jj = idx & 7, bb = (idx >> 3) & 31, aa = idx >> 8;
        tile[aa][bb][jj] = K[((size_t)(a0 + aa) * 256 + (b0 + bb)) * 64 + (j0 + jj)];
    }
    __syncthreads();

    for (int idx = t; idx < 4096; idx += 256) {
        const int p = idx & 15, aa = (idx >> 4) & 31, jj = idx >> 9;
        const float f0 = tile[aa][2*p][jj], f1 = tile[aa][2*p+1][jj];
        const _Float16 h0 = (_Float16)f0, h1 = (_Float16)f1;
        const f16x2 hv = {h0, h1};
        const f16x2 lv = {(_Float16)(f0 - (float)h0), (_Float16)(f1 - (float)h1)};
        const size_t off = ((size_t)(j0 + jj) * 256 + (a0 + aa)) * 256 + (b0 + 2*p);
        *(f16x2*)(B1h + off) = hv;
        *(f16x2*)(B1l + off) = lv;
    }
    for (int idx = t; idx < 4096; idx += 256) {
        const int p = idx & 15, bb = (idx >> 4) & 31, jj = idx >> 9;
        const float f0 = tile[2*p][bb][jj], f1 = tile[2*p+1][bb][jj];
        const _Float16 h0 = (_Float16)f0, h1 = (_Float16)f1;
        const f16x2 hv = {h0, h1};
        const f16x2 lv = {(_Float16)(f0 - (float)h0), (_Float16)(f1 - (float)h1)};
        const size_t off = ((size_t)(j0 + jj) * 256 + (b0 + bb)) * 256 + (a0 + 2*p);
        *(f16x2*)(B2h + off) = hv;
        *(f16x2*)(B2l + off) = lv;
    }
}

// ---------------- fused recurrence ----------------
// One half-layer: D = Ain @ B  (M=32,N=256,K=256, 16x16x32 f16 MFMA, 3-split),
// then master += H*tanh(bias +/- D), write fp16 hi/lo of master to Aout LDS.
// Per wave: 1 m-tile (mt), 2 n-tiles (nr*2 .. nr*2+1).
template<bool NEG>
__device__ __forceinline__ void half_layer(
    const _Float16* __restrict__ Ain_h, const _Float16* __restrict__ Ain_l,
    _Float16* __restrict__ Aout_h, _Float16* __restrict__ Aout_l,
    const _Float16* __restrict__ Bh, const _Float16* __restrict__ Bl,
    const float* __restrict__ bias,            // pre-offset: bvec + featbase*64 + j
    float (&M)[2][4],
    const int mt, const int nr, const int l15, const int hi4)
{
    f32x4 acc[2] = {{0.f,0.f,0.f,0.f},{0.f,0.f,0.f,0.f}};
    const int arow = mt * 16 + l15;
#pragma unroll
    for (int s = 0; s < 8; ++s) {
        const int k0 = s * 32 + hi4 * 8;
        const f16x8 ah = *(const f16x8*)(Ain_h + swz(arow, k0));
        const f16x8 al = *(const f16x8*)(Ain_l + swz(arow, k0));
#pragma unroll
        for (int nt = 0; nt < 2; ++nt) {
            const int n = (nr * 2 + nt) * 16 + l15;
            const size_t boff = (size_t)n * 256 + k0;
            const f16x8 bh = *(const f16x8*)(Bh + boff);
            const f16x8 bl = *(const f16x8*)(Bl + boff);
            acc[nt] = __builtin_amdgcn_mfma_f32_16x16x32_f16(ah, bh, acc[nt], 0, 0, 0);
            acc[nt] = __builtin_amdgcn_mfma_f32_16x16x32_f16(al, bh, acc[nt], 0, 0, 0);
            acc[nt] = __builtin_amdgcn_mfma_f32_16x16x32_f16(ah, bl, acc[nt], 0, 0, 0);
        }
    }
#pragma unroll
    for (int nt = 0; nt < 2; ++nt) {
        const int n = (nr * 2 + nt) * 16 + l15;
        const float bv = bias[(size_t)n * 64];
#pragma unroll
        for (int q = 0; q < 4; ++q) {
            const int m = mt * 16 + hi4 * 4 + q;
            const float x = NEG ? (bv - acc[nt][q]) : (acc[nt][q] + bv);
            const float v = M[nt][q] + H_STEP * fast_tanh(x);
            M[nt][q] = v;
            const _Float16 vh = (_Float16)v;
            const int o = swz(m, n);
            Aout_h[o] = vh;
            Aout_l[o] = (_Float16)(v - (float)vh);
        }
    }
}

__global__ __launch_bounds__(1024, 4) void ms1_main(
    const float* __restrict__ Y0,
    const float* __restrict__ bvec,
    const _Float16* __restrict__ B1h, const _Float16* __restrict__ B1l,
    const _Float16* __restrict__ B2h, const _Float16* __restrict__ B2l,
    float* __restrict__ out)
{
    __shared__ _Float16 Yh[8192], Yl[8192], Zh[8192], Zl[8192];  // 64 KB total

    const int tid  = threadIdx.x;
    const int lane = tid & 63, w = tid >> 6;  // 16 waves
    const int mt = w & 1, nr = w >> 1;        // wave -> (m-tile, n-range of 32)
    const int l15 = lane & 15, hi4 = lane >> 4;
    const size_t row0 = (size_t)blockIdx.x * 32;

    float Ym[2][4], Zm[2][4];   // fp32 master state, register-resident

#pragma unroll
    for (int nt = 0; nt < 2; ++nt) {
        const int n = (nr * 2 + nt) * 16 + l15;
#pragma unroll
        for (int q = 0; q < 4; ++q) {
            const int m = mt * 16 + hi4 * 4 + q;
            const size_t base = (row0 + m) * 512;
            const float y = Y0[base + n];
            const float z = Y0[base + 256 + n];
            Ym[nt][q] = y; Zm[nt][q] = z;
            const _Float16 yh = (_Float16)y;
            const int o = swz(m, n);
            Yh[o] = yh;
            Yl[o] = (_Float16)(y - (float)yh);
        }
    }
    __syncthreads();

    for (int j = 0; j < 64; ++j) {
        const size_t jb = (size_t)j << 16;  // j * 256*256
        // Z += H*tanh(Y @ K^T + b[256:])
        half_layer<false>(Yh, Yl, Zh, Zl, B1h + jb, B1l + jb,
                          bvec + 256 * 64 + j, Zm, mt, nr, l15, hi4);
        __syncthreads();
        // Y += H*tanh(b[:256] - Z @ K)
        half_layer<true>(Zh, Zl, Yh, Yl, B2h + jb, B2l + jb,
                         bvec + j, Ym, mt, nr, l15, hi4);
        __syncthreads();
    }

#pragma unroll
    for (int nt = 0; nt < 2; ++nt) {
        const int n = (nr * 2 + nt) * 16 + l15;
#pragma unroll
        for (int q = 0; q < 4; ++q) {
            const int m = mt * 16 + hi4 * 4 + q;
            const size_t base = (row0 + m) * 512;
            out[base + n]       = Ym[nt][q];
            out[base + 256 + n] = Zm[nt][q];
        }
    }
}

extern "C" void kernel_launch(void* const* d_in, const int* in_sizes, int n_in,
                              void* d_out, int out_size, void* d_ws, size_t ws_size,
                              hipStream_t stream) {
    (void)in_sizes; (void)n_in; (void)out_size;
    const float* Y0 = (const float*)d_in[0];
    const float* K  = (const float*)d_in[1];
    const float* b  = (const float*)d_in[2];

    const size_t ARR = (size_t)64 * 256 * 256;     // elements per half array
    if (ws_size < 4 * ARR * sizeof(_Float16)) return;

    _Float16* B1h = (_Float16*)d_ws;
    _Float16* B1l = B1h + ARR;
    _Float16* B2h = B1l + ARR;
    _Float16* B2l = B2h + ARR;

    prep_split<<<512, 256, 0, stream>>>(K, B1h, B1l, B2h, B2l);
    ms1_main<<<256, 1024, 0, stream>>>(Y0, b, B1h, B1l, B2h, B2l, (float*)d_out);
}

// Round 3
// 675.370 us; speedup vs baseline: 3.6141x; 3.0071x over previous
//
#include <hip/hip_runtime.h>

// MS1: 64-layer reversible net, fused single-kernel recurrence.
//   Z += H*tanh(Y @ K_j^T + b_j[256:]);  Y += H*tanh(b_j[:256] - Z @ K_j)
// R3: reg-staged B pipeline (depth 2) through double-buffered LDS, raw
// s_barrier (never drains vmcnt), counted waits left to the compiler.
// 256 blocks x 32 rows, 1024 threads (16 waves). 128 KB dynamic LDS:
// state hi/lo 64 KB + 2 x 32 KB B tile buffers. 3-pass f16 Ozaki MFMA.

typedef _Float16 f16x8 __attribute__((ext_vector_type(8)));
typedef _Float16 f16x2 __attribute__((ext_vector_type(2)));
typedef float    f32x4 __attribute__((ext_vector_type(4)));

#define H_STEP 0.015625f   // 1/64

// LDS layout in halfs (total 65536 halfs = 128 KB dynamic)
#define ST_YH 0
#define ST_YL 8192
#define ST_ZH 16384
#define ST_ZL 24576
#define BB0   32768
#define BB1   49152

__device__ __forceinline__ float fast_tanh(float x) {
    float xc = fminf(fmaxf(x, -9.0f), 9.0f);
    float t  = __builtin_amdgcn_exp2f(xc * 2.8853900817779268f); // 2x*log2(e)
    return (t - 1.0f) * __builtin_amdgcn_rcpf(t + 1.0f);
}

// state LDS index with XOR swizzle (16B-granular column rotation per row)
__device__ __forceinline__ int swz(int m, int k) {
    return (m << 8) + (k ^ ((m & 7) << 3));
}
// B-tile LDS index (within one arr): row n (32 halfs), chunk kc swizzled
__device__ __forceinline__ int bswz(int n, int kc) {
    return n * 32 + ((kc ^ ((n >> 1) & 3)) << 3);
}

// ---------------- prep: K[a][b][j] -> fragment-friendly half arrays ----------
// B1[j][n][k] = K[n][k][j]  (for Y @ K^T);  B2[j][n][k] = K[k][n][j]  (Z @ K)
__global__ __launch_bounds__(256) void prep_split(
    const float* __restrict__ K,
    _Float16* __restrict__ B1h, _Float16* __restrict__ B1l,
    _Float16* __restrict__ B2h, _Float16* __restrict__ B2l)
{
    __shared__ float tile[32][33][9];
    const int a0 = (blockIdx.x & 7) << 5;
    const int b0 = ((blockIdx.x >> 3) & 7) << 5;
    const int j0 = (blockIdx.x >> 6) << 3;
    const int t = threadIdx.x;

    for (int idx = t; idx < 8192; idx += 256) {
        const int jj = idx & 7, bb = (idx >> 3) & 31, aa = idx >> 8;
        tile[aa][bb][jj] = K[((size_t)(a0 + aa) * 256 + (b0 + bb)) * 64 + (j0 + jj)];
    }
    __syncthreads();

    for (int idx = t; idx < 4096; idx += 256) {
        const int p = idx & 15, aa = (idx >> 4) & 31, jj = idx >> 9;
        const float f0 = tile[aa][2*p][jj], f1 = tile[aa][2*p+1][jj];
        const _Float16 h0 = (_Float16)f0, h1 = (_Float16)f1;
        const f16x2 hv = {h0, h1};
        const f16x2 lv = {(_Float16)(f0 - (float)h0), (_Float16)(f1 - (float)h1)};
        const size_t off = ((size_t)(j0 + jj) * 256 + (a0 + aa)) * 256 + (b0 + 2*p);
        *(f16x2*)(B1h + off) = hv;
        *(f16x2*)(B1l + off) = lv;
    }
    for (int idx = t; idx < 4096; idx += 256) {
        const int p = idx & 15, bb = (idx >> 4) & 31, jj = idx >> 9;
        const float f0 = tile[2*p][bb][jj], f1 = tile[2*p+1][bb][jj];
        const _Float16 h0 = (_Float16)f0, h1 = (_Float16)f1;
        const f16x2 hv = {h0, h1};
        const f16x2 lv = {(_Float16)(f0 - (float)h0), (_Float16)(f1 - (float)h1)};
        const size_t off = ((size_t)(j0 + jj) * 256 + (b0 + bb)) * 256 + (a0 + 2*p);
        *(f16x2*)(B2h + off) = hv;
        *(f16x2*)(B2l + off) = lv;
    }
}

// ---------------- one half-layer (8 pipelined k-tiles + epilogue) ------------
template<bool NEG>
__device__ __forceinline__ void phase(
    _Float16* lds, const int stA, const int stO,
    const _Float16* __restrict__ Bh,  const _Float16* __restrict__ Bl,
    const _Float16* __restrict__ BhN, const _Float16* __restrict__ BlN,
    const float* __restrict__ bias,       // pre-offset: bvec + featbase*64 + j
    float (&M)[2][4],
    f16x8& p0h, f16x8& p0l, f16x8& p1h, f16x8& p1l,
    const int srcoff, const int dstoff,
    const int arow, const int n0, const int n1,
    const int boff0, const int boff1, const int hi4, const int mt)
{
    const float bv0 = bias[(size_t)n0 * 64];
    const float bv1 = bias[(size_t)n1 * 64];

    f32x4 acc0 = {0.f,0.f,0.f,0.f}, acc1 = {0.f,0.f,0.f,0.f};

#pragma unroll
    for (int kt = 0; kt < 8; ++kt) {
        _Float16* bb = lds + ((kt & 1) ? BB1 : BB0);
        // W(kt): commit regs prefetched 2 tiles ago into buf[kt&1]
        if ((kt & 1) == 0) {
            *(f16x8*)(bb + dstoff)        = p0h;
            *(f16x8*)(bb + 8192 + dstoff) = p0l;
        } else {
            *(f16x8*)(bb + dstoff)        = p1h;
            *(f16x8*)(bb + 8192 + dstoff) = p1l;
        }
        // L(kt+2): issue next loads (cross into next phase's B at kt=6,7)
        {
            const _Float16* sh; const _Float16* sl; int toff;
            if (kt < 6) { sh = Bh;  sl = Bl;  toff = (kt + 2) * 32; }
            else        { sh = BhN; sl = BlN; toff = (kt - 6) * 32; }
            if ((kt & 1) == 0) {
                p0h = *(const f16x8*)(sh + srcoff + toff);
                p0l = *(const f16x8*)(sl + srcoff + toff);
            } else {
                p1h = *(const f16x8*)(sh + srcoff + toff);
                p1l = *(const f16x8*)(sl + srcoff + toff);
            }
        }
        // my LDS ops (incl. W(kt) and prior reads) complete -> signal
        asm volatile("s_waitcnt lgkmcnt(0)" ::: "memory");
        __builtin_amdgcn_s_barrier();            // raw: does NOT drain vmcnt
        __builtin_amdgcn_sched_barrier(0);       // no ds_read hoisting above
        // C(kt)
        const int k0 = kt * 32 + hi4 * 8;
        const f16x8 ah = *(const f16x8*)(lds + stA + swz(arow, k0));
        const f16x8 al = *(const f16x8*)(lds + stA + 8192 + swz(arow, k0));
        const f16x8 bh0 = *(const f16x8*)(bb + boff0);
        const f16x8 bl0 = *(const f16x8*)(bb + 8192 + boff0);
        const f16x8 bh1 = *(const f16x8*)(bb + boff1);
        const f16x8 bl1 = *(const f16x8*)(bb + 8192 + boff1);
        acc0 = __builtin_amdgcn_mfma_f32_16x16x32_f16(ah, bh0, acc0, 0, 0, 0);
        acc1 = __builtin_amdgcn_mfma_f32_16x16x32_f16(ah, bh1, acc1, 0, 0, 0);
        acc0 = __builtin_amdgcn_mfma_f32_16x16x32_f16(al, bh0, acc0, 0, 0, 0);
        acc1 = __builtin_amdgcn_mfma_f32_16x16x32_f16(al, bh1, acc1, 0, 0, 0);
        acc0 = __builtin_amdgcn_mfma_f32_16x16x32_f16(ah, bl0, acc0, 0, 0, 0);
        acc1 = __builtin_amdgcn_mfma_f32_16x16x32_f16(ah, bl1, acc1, 0, 0, 0);
    }
    // epilogue: master += H*tanh(bias +/- acc), re-split state to LDS
#pragma unroll
    for (int q = 0; q < 4; ++q) {
        const int m = mt * 16 + hi4 * 4 + q;
        {
            const float x = NEG ? (bv0 - acc0[q]) : (acc0[q] + bv0);
            const float v = M[0][q] + H_STEP * fast_tanh(x);
            M[0][q] = v;
            const _Float16 vh = (_Float16)v;
            const int o = swz(m, n0);
            lds[stO + o] = vh;
            lds[stO + 8192 + o] = (_Float16)(v - (float)vh);
        }
        {
            const float x = NEG ? (bv1 - acc1[q]) : (acc1[q] + bv1);
            const float v = M[1][q] + H_STEP * fast_tanh(x);
            M[1][q] = v;
            const _Float16 vh = (_Float16)v;
            const int o = swz(m, n1);
            lds[stO + o] = vh;
            lds[stO + 8192 + o] = (_Float16)(v - (float)vh);
        }
    }
}

__global__ __launch_bounds__(1024, 4) void ms1_main(
    const float* __restrict__ Y0,
    const float* __restrict__ bvec,
    const _Float16* __restrict__ B1h, const _Float16* __restrict__ B1l,
    const _Float16* __restrict__ B2h, const _Float16* __restrict__ B2l,
    float* __restrict__ out)
{
    extern __shared__ _Float16 lds[];

    const int tid  = threadIdx.x;
    const int lane = tid & 63, w = tid >> 6;   // 16 waves
    const int mt = w & 1, nr = w >> 1;
    const int l15 = lane & 15, hi4 = lane >> 4;
    const size_t row0 = (size_t)blockIdx.x * 32;

    const int arow  = mt * 16 + l15;
    const int n0    = (nr * 2 + 0) * 16 + l15;
    const int n1    = (nr * 2 + 1) * 16 + l15;
    const int boff0 = bswz(n0, hi4);
    const int boff1 = bswz(n1, hi4);

    // staging geometry: wave w stages n-rows [w*16, w*16+16), lane covers
    // (row = w*16 + lane/4, k-chunk = lane%3... lane&3) -> coalesced 64B/4 lanes
    const int sn     = w * 16 + (lane >> 2);
    const int kc     = lane & 3;
    const int srcoff = sn * 256 + kc * 8;    // halfs, + kt*32 + j*65536
    const int dstoff = bswz(sn, kc);         // halfs, + arr*8192 (+BBx)

    float Ym[2][4], Zm[2][4];

    // initial state: masters to regs, Y hi/lo to LDS (Z LDS filled by phase 1)
#pragma unroll
    for (int nt = 0; nt < 2; ++nt) {
        const int n = nt ? n1 : n0;
#pragma unroll
        for (int q = 0; q < 4; ++q) {
            const int m = mt * 16 + hi4 * 4 + q;
            const size_t base = (row0 + m) * 512;
            const float y = Y0[base + n];
            const float z = Y0[base + 256 + n];
            Ym[nt][q] = y; Zm[nt][q] = z;
            const _Float16 yh = (_Float16)y;
            const int o = swz(m, n);
            lds[ST_YH + o] = yh;
            lds[ST_YL + o] = (_Float16)(y - (float)yh);
        }
    }

    // prologue: prefetch phase-0 tiles 0,1
    f16x8 p0h = *(const f16x8*)(B1h + srcoff);
    f16x8 p0l = *(const f16x8*)(B1l + srcoff);
    f16x8 p1h = *(const f16x8*)(B1h + srcoff + 32);
    f16x8 p1l = *(const f16x8*)(B1l + srcoff + 32);

    for (int j = 0; j < 64; ++j) {
        const size_t jb  = (size_t)j << 16;
        const size_t jbn = (j < 63) ? ((size_t)(j + 1) << 16) : 0; // wrap: dead prefetch
        // Z += H*tanh(Y @ K^T + b[256:])
        phase<false>(lds, ST_YH, ST_ZH, B1h + jb, B1l + jb, B2h + jb, B2l + jb,
                     bvec + 256 * 64 + j, Zm, p0h, p0l, p1h, p1l,
                     srcoff, dstoff, arow, n0, n1, boff0, boff1, hi4, mt);
        // Y += H*tanh(b[:256] - Z @ K)
        phase<true>(lds, ST_ZH, ST_YH, B2h + jb, B2l + jb, B1h + jbn, B1l + jbn,
                    bvec + j, Ym, p0h, p0l, p1h, p1l,
                    srcoff, dstoff, arow, n0, n1, boff0, boff1, hi4, mt);
    }

#pragma unroll
    for (int nt = 0; nt < 2; ++nt) {
        const int n = nt ? n1 : n0;
#pragma unroll
        for (int q = 0; q < 4; ++q) {
            const int m = mt * 16 + hi4 * 4 + q;
            const size_t base = (row0 + m) * 512;
            out[base + n]       = Ym[nt][q];
            out[base + 256 + n] = Zm[nt][q];
        }
    }
}

extern "C" void kernel_launch(void* const* d_in, const int* in_sizes, int n_in,
                              void* d_out, int out_size, void* d_ws, size_t ws_size,
                              hipStream_t stream) {
    (void)in_sizes; (void)n_in; (void)out_size;
    const float* Y0 = (const float*)d_in[0];
    const float* K  = (const float*)d_in[1];
    const float* b  = (const float*)d_in[2];

    const size_t ARR = (size_t)64 * 256 * 256;
    if (ws_size < 4 * ARR * sizeof(_Float16)) return;

    _Float16* B1h = (_Float16*)d_ws;
    _Float16* B1l = B1h + ARR;
    _Float16* B2h = B1l + ARR;
    _Float16* B2l = B2h + ARR;

    hipFuncSetAttribute((const void*)ms1_main,
                        hipFuncAttributeMaxDynamicSharedMemorySize, 131072);

    prep_split<<<512, 256, 0, stream>>>(K, B1h, B1l, B2h, B2l);
    ms1_main<<<256, 1024, 131072, stream>>>(Y0, b, B1h, B1l, B2h, B2l, (float*)d_out);
}